// Round 12
// baseline (1278.826 us; speedup 1.0000x reference)
//
#include <hip/hip_runtime.h>
#include <hip/hip_bf16.h>
#include <math.h>

typedef __attribute__((ext_vector_type(8))) short short8;
typedef __attribute__((ext_vector_type(4))) float f32x4;
typedef __attribute__((ext_vector_type(4))) unsigned short us4;

#define MFMA_BF16 __builtin_amdgcn_mfma_f32_16x16x32_bf16

__device__ __forceinline__ float b2f(unsigned short u) {
    union { unsigned int i; float f; } v; v.i = ((unsigned int)u) << 16; return v.f;
}
__device__ __forceinline__ unsigned short f2b(float f) {
    __hip_bfloat16 h = __float2bfloat16(f);
    return *reinterpret_cast<unsigned short*>(&h);
}

// ---------------------------------------------------------------------------
// K0: transpose h_grid -> ht (bf16 channels-last). rep=1 (known ~50us).
// ---------------------------------------------------------------------------
__global__ __launch_bounds__(256) void transpose_h(const float* __restrict__ hg,
                                                   unsigned short* __restrict__ ht) {
    __shared__ float t[128][65];
    int bid = blockIdx.x;                        // 8192 = 8 xcd * 1024
    int x = bid & 7, r = bid >> 3;
    int n = x * 16 + (r & 15);
    int pb = r >> 4;
    int tid = threadIdx.x;
    const float* src = hg + (size_t)n * 128 * 4096 + pb * 64;
    int j = tid & 63, i0 = tid >> 6;
#pragma unroll
    for (int ii = 0; ii < 32; ++ii) {
        int ch = ii * 4 + i0;
        t[ch][j] = src[(size_t)ch * 4096 + j];
    }
    __syncthreads();
#pragma unroll
    for (int it = 0; it < 8; ++it) {
        int idx = tid + it * 256;
        int px = idx >> 5, cq = idx & 31;
        us4 o;
#pragma unroll
        for (int rr = 0; rr < 4; ++rr) o[rr] = f2b(t[cq * 4 + rr][px]);
        *(us4*)&ht[((size_t)n * 4096 + pb * 64 + px) * 128 + cq * 4] = o;
    }
}

// ---------------------------------------------------------------------------
// prep: all weight layouts. rep=8 (visibility probe).
// ---------------------------------------------------------------------------
#define PREP 8
__global__ void prep_weights(const float* __restrict__ W0, const float* __restrict__ W1,
                             const float* __restrict__ W2,
                             unsigned short* __restrict__ w0t,  unsigned short* __restrict__ w0st,
                             unsigned short* __restrict__ w0ft, unsigned short* __restrict__ w1t,
                             unsigned short* __restrict__ w2p) {
    int i = blockIdx.x * 256 + threadIdx.x;
#pragma unroll 1
    for (int rep = 0; rep < PREP; ++rep) {
        for (int idx = i; idx < 128 * 384; idx += gridDim.x * 256) {   // w0t[j][k<384]
            int j = idx / 384, k = idx - j * 384;
            w0t[idx] = f2b(W0[k * 128 + j]);
        }
        for (int idx = i; idx < 128 * 128; idx += gridDim.x * 256) {   // w0st[j][k<128]
            int j = idx >> 7, k = idx & 127;
            w0st[idx] = f2b(W0[k * 128 + j]);
        }
        for (int idx = i; idx < 128 * 256; idx += gridDim.x * 256) {   // w0ft[j][k<256]
            int j = idx >> 8, k = idx & 255;
            w0ft[idx] = f2b(W0[(128 + k) * 128 + j]);
        }
        for (int idx = i; idx < 128 * 128; idx += gridDim.x * 256) {   // w1t
            int j = idx >> 7, k = idx & 127;
            w1t[idx] = f2b(W1[k * 128 + j]);
        }
        for (int idx = i; idx < 16 * 128; idx += gridDim.x * 256) {    // w2p
            int r = idx >> 7, k = idx & 127;
            w2p[idx] = (r < 2) ? f2b(W2[k * 2 + r]) : (unsigned short)0;
        }
    }
}

// ---------------------------------------------------------------------------
// R10 fused (no-spill design). rep=2: first-ever spill/occupancy counters.
// ---------------------------------------------------------------------------
#define W0P 784
#define HBP 272
#define FREP 2

__global__ __launch_bounds__(512, 2) void fused_decoder(
    const unsigned short* __restrict__ ht,
    const float* __restrict__ xs, const float* __restrict__ ys,
    const float* __restrict__ Bm,
    const unsigned short* __restrict__ w0t, const float* __restrict__ b0,
    const unsigned short* __restrict__ w1t, const float* __restrict__ b1,
    const unsigned short* __restrict__ w2p, const float* __restrict__ b2,
    float* __restrict__ out)
{
    __shared__ char smem[128 * W0P + 8 * 16 * HBP];
    char* w0s = smem;
    int tid = threadIdx.x, lane = tid & 63, w = tid >> 6;
    int lr = lane & 15, lg = lane >> 4;
    char* hb = smem + 128 * W0P + w * 16 * HBP;

    {
        const short8* src = (const short8*)w0t;
#pragma unroll 1
        for (int it = 0; it < 12; ++it) {
            int c = tid + it * 512;
            int row = c / 48, cc = c - row * 48;
            *(short8*)(w0s + row * W0P + cc * 16) = src[c];
        }
    }
    __syncthreads();

    int bid = blockIdx.x;
    int x = bid & 7, s = bid >> 3;
    int n = x * 16 + (s >> 3);
    int pt = s & 7;
    int gp0 = n * 2048 + pt * 256 + w * 32;
    const char* base = (const char*)ht + ((size_t)n << 20) + lg * 16;

#pragma unroll 1
    for (int rep = 0; rep < FREP; ++rep) {
        float xm[2], ym[2], wxv[2], wyv[2];
        int o00[2], o01[2], o10[2], o11[2];
#pragma unroll
        for (int m = 0; m < 2; ++m) {
            int gp = gp0 + m * 16 + lr;
            float xc = xs[gp], yc = ys[gp];
            xm[m] = xc; ym[m] = yc;
            float px = xc * 63.f, py = yc * 63.f;
            float x0f = fminf(fmaxf(floorf(px), 0.f), 63.f);
            float y0f = fminf(fmaxf(floorf(py), 0.f), 63.f);
            wxv[m] = px - x0f; wyv[m] = py - y0f;
            int xi0 = (int)x0f, yi0 = (int)y0f;
            int xi1 = min(xi0 + 1, 63), yi1 = min(yi0 + 1, 63);
            o00[m] = (yi0 * 64 + xi0) * 256;
            o01[m] = (yi0 * 64 + xi1) * 256;
            o10[m] = (yi1 * 64 + xi0) * 256;
            o11[m] = (yi1 * 64 + xi1) * 256;
        }

        f32x4 acc[2][8];
#pragma unroll
        for (int nj = 0; nj < 8; ++nj) {
            float bv = b0[nj * 16 + lr];
            acc[0][nj] = (f32x4){bv, bv, bv, bv};
            acc[1][nj] = acc[0][nj];
        }

        short8 c00[2], c01[2], c10[2], c11[2];
#pragma unroll
        for (int m = 0; m < 2; ++m) {
            c00[m] = *(const short8*)(base + o00[m]);
            c01[m] = *(const short8*)(base + o01[m]);
            c10[m] = *(const short8*)(base + o10[m]);
            c11[m] = *(const short8*)(base + o11[m]);
        }

#pragma unroll 1
        for (int q = 0; q < 4; ++q) {
            short8 asn[2], acs[2];
            {
                int f0 = q * 32 + lg * 8;
                f32x4 B0a = *(const f32x4*)&Bm[f0];
                f32x4 B0b = *(const f32x4*)&Bm[f0 + 4];
                f32x4 B1a = *(const f32x4*)&Bm[128 + f0];
                f32x4 B1b = *(const f32x4*)&Bm[128 + f0 + 4];
#pragma unroll
                for (int m = 0; m < 2; ++m) {
                    float t_[8];
#pragma unroll
                    for (int jj = 0; jj < 4; ++jj) {
                        t_[jj]     = xm[m] * B0a[jj] + ym[m] * B1a[jj];
                        t_[4 + jj] = xm[m] * B0b[jj] + ym[m] * B1b[jj];
                    }
#pragma unroll
                    for (int jj = 0; jj < 8; ++jj) {
                        float tf = t_[jj] - floorf(t_[jj]);
                        float sv, cv;
                        asm("v_sin_f32 %0, %1" : "=v"(sv) : "v"(tf));
                        asm("v_cos_f32 %0, %1" : "=v"(cv) : "v"(tf));
                        asn[m][jj] = (short)f2b(sv);
                        acs[m][jj] = (short)f2b(cv);
                    }
                }
            }
#pragma unroll
            for (int nj = 0; nj < 8; ++nj) {
                short8 bs = *(const short8*)(w0s + (nj * 16 + lr) * W0P + (4 + q) * 64 + lg * 16);
                acc[0][nj] = MFMA_BF16(asn[0], bs, acc[0][nj], 0, 0, 0);
                acc[1][nj] = MFMA_BF16(asn[1], bs, acc[1][nj], 0, 0, 0);
            }
#pragma unroll
            for (int nj = 0; nj < 8; ++nj) {
                short8 bc = *(const short8*)(w0s + (nj * 16 + lr) * W0P + (8 + q) * 64 + lg * 16);
                acc[0][nj] = MFMA_BF16(acs[0], bc, acc[0][nj], 0, 0, 0);
                acc[1][nj] = MFMA_BF16(acs[1], bc, acc[1][nj], 0, 0, 0);
            }
            short8 a[2];
#pragma unroll
            for (int m = 0; m < 2; ++m) {
                float wx = wxv[m], wy = wyv[m];
                float ivx = 1.f - wx, ivy = 1.f - wy;
#pragma unroll
                for (int jj = 0; jj < 8; ++jj) {
                    float top = b2f((unsigned short)c00[m][jj]) * ivx + b2f((unsigned short)c01[m][jj]) * wx;
                    float bot = b2f((unsigned short)c10[m][jj]) * ivx + b2f((unsigned short)c11[m][jj]) * wx;
                    a[m][jj] = (short)f2b(top * ivy + bot * wy);
                }
            }
            if (q < 3) {
                int so = (q + 1) * 64;
#pragma unroll
                for (int m = 0; m < 2; ++m) {
                    c00[m] = *(const short8*)(base + o00[m] + so);
                    c01[m] = *(const short8*)(base + o01[m] + so);
                    c10[m] = *(const short8*)(base + o10[m] + so);
                    c11[m] = *(const short8*)(base + o11[m] + so);
                }
            }
#pragma unroll
            for (int nj = 0; nj < 8; ++nj) {
                short8 b = *(const short8*)(w0s + (nj * 16 + lr) * W0P + q * 64 + lg * 16);
                acc[0][nj] = MFMA_BF16(a[0], b, acc[0][nj], 0, 0, 0);
                acc[1][nj] = MFMA_BF16(a[1], b, acc[1][nj], 0, 0, 0);
            }
        }

        float bb2 = (lr < 2) ? b2[lr] : 0.f;
#pragma unroll
        for (int m = 0; m < 2; ++m) {
#pragma unroll
            for (int nj = 0; nj < 8; ++nj)
#pragma unroll
                for (int r = 0; r < 4; ++r) {
                    int row = lg * 4 + r;
                    *(unsigned short*)(hb + row * HBP + (nj * 16 + lr) * 2) =
                        f2b(fmaxf(acc[m][nj][r], 0.f));
                }
            asm volatile("s_waitcnt lgkmcnt(0)" ::: "memory");
            short8 a1[4];
#pragma unroll
            for (int ks = 0; ks < 4; ++ks)
                a1[ks] = *(const short8*)(hb + lr * HBP + ks * 64 + lg * 16);
            asm volatile("s_waitcnt lgkmcnt(0)" ::: "memory");

#pragma unroll
            for (int nj = 0; nj < 8; ++nj) {
                float bv = b1[nj * 16 + lr];
                acc[m][nj] = (f32x4){bv, bv, bv, bv};
            }
#pragma unroll
            for (int ks = 0; ks < 4; ++ks)
#pragma unroll
                for (int nj = 0; nj < 8; ++nj) {
                    short8 b = *(const short8*)&w1t[(nj * 16 + lr) * 128 + ks * 32 + lg * 8];
                    acc[m][nj] = MFMA_BF16(a1[ks], b, acc[m][nj], 0, 0, 0);
                }

#pragma unroll
            for (int nj = 0; nj < 8; ++nj)
#pragma unroll
                for (int r = 0; r < 4; ++r) {
                    int row = lg * 4 + r;
                    *(unsigned short*)(hb + row * HBP + (nj * 16 + lr) * 2) =
                        f2b(fmaxf(acc[m][nj][r], 0.f));
                }
            asm volatile("s_waitcnt lgkmcnt(0)" ::: "memory");

            f32x4 acc2 = (f32x4){bb2, bb2, bb2, bb2};
#pragma unroll
            for (int ks = 0; ks < 4; ++ks) {
                short8 a2 = *(const short8*)(hb + lr * HBP + ks * 64 + lg * 16);
                short8 bz = *(const short8*)&w2p[lr * 128 + ks * 32 + lg * 8];
                acc2 = MFMA_BF16(a2, bz, acc2, 0, 0, 0);
            }
            asm volatile("s_waitcnt lgkmcnt(0)" ::: "memory");
            if (lr < 2) {
#pragma unroll
                for (int r = 0; r < 4; ++r) {
                    int gpo = gp0 + m * 16 + lg * 4 + r;
                    float v = acc2[r];
                    if (lr == 0) {
                        out[gpo * 2] = v;
                    } else {
                        float sp = (v > 20.f) ? v : log1pf(expf(v));
                        out[gpo * 2 + 1] = sp + 0.01f;
                    }
                }
            }
        }
    }
}

// ---------------------------------------------------------------------------
// R11 K0': proj_h, rep=2.
// ---------------------------------------------------------------------------
#define PJREP 2
__global__ __launch_bounds__(256, 2) void proj_h(const float* __restrict__ hg,
                                                 const unsigned short* __restrict__ w0st,
                                                 unsigned short* __restrict__ P) {
    __shared__ float t[128][65];
    __shared__ unsigned short ws[128][136];
    int bid = blockIdx.x;
    int x = bid & 7, r = bid >> 3;
    int n = x * 16 + (r & 15);
    int pb = r >> 4;
    int tid = threadIdx.x;
    {
        const short8* src = (const short8*)w0st;
#pragma unroll
        for (int it = 0; it < 8; ++it) {
            int c = tid + it * 256;
            int row = c >> 4, cc = c & 15;
            *(short8*)&ws[row][cc * 8] = src[c];
        }
    }
    const float* src = hg + (size_t)n * 128 * 4096 + pb * 64;
    int j = tid & 63, i0 = tid >> 6;
    int lane = tid & 63, w = tid >> 6, lr = lane & 15, lg = lane >> 4;

#pragma unroll 1
    for (int rep = 0; rep < PJREP; ++rep) {
#pragma unroll
        for (int ii = 0; ii < 32; ++ii) {
            int ch = ii * 4 + i0;
            t[ch][j] = src[(size_t)ch * 4096 + j];
        }
        __syncthreads();

        short8 afr[4];
#pragma unroll
        for (int ks = 0; ks < 4; ++ks) {
            int px = w * 16 + lr;
#pragma unroll
            for (int jj = 0; jj < 8; ++jj)
                afr[ks][jj] = (short)f2b(t[ks * 32 + lg * 8 + jj][px]);
        }
        __syncthreads();

        f32x4 acc[8];
#pragma unroll
        for (int nj = 0; nj < 8; ++nj) acc[nj] = (f32x4){0.f, 0.f, 0.f, 0.f};
#pragma unroll
        for (int ks = 0; ks < 4; ++ks)
#pragma unroll
            for (int nj = 0; nj < 8; ++nj) {
                short8 b = *(const short8*)&ws[nj * 16 + lr][ks * 32 + lg * 8];
                acc[nj] = MFMA_BF16(afr[ks], b, acc[nj], 0, 0, 0);
            }

        unsigned short* tb = (unsigned short*)t;
#pragma unroll
        for (int nj = 0; nj < 8; ++nj)
#pragma unroll
            for (int r4 = 0; r4 < 4; ++r4)
                tb[(w * 16 + lg * 4 + r4) * 136 + nj * 16 + lr] = f2b(acc[nj][r4]);
        __syncthreads();
        us4* dst = (us4*)(P + ((size_t)n * 4096 + pb * 64) * 128);
#pragma unroll
        for (int it = 0; it < 8; ++it) {
            int idx = tid + it * 256;
            int px = idx >> 5, c4 = idx & 31;
            dst[px * 32 + c4] = *(us4*)&tb[px * 136 + c4 * 4];
        }
        __syncthreads();
    }
}

// ---------------------------------------------------------------------------
// R11 K1': spatial_F, rep=4.
// ---------------------------------------------------------------------------
#define SFREP 4
__global__ __launch_bounds__(256, 3) void spatial_F(
    const float* __restrict__ xs, const float* __restrict__ ys,
    const float* __restrict__ Bm, const unsigned short* __restrict__ w0ft,
    const float* __restrict__ b0, unsigned short* __restrict__ F) {
    __shared__ unsigned short hb[4][16][136];
    int tid = threadIdx.x, lane = tid & 63, w = tid >> 6;
    int lr = lane & 15, lg = lane >> 4;
    int bid = blockIdx.x;
    int x = bid & 7, s = bid >> 3;
    int n = x * 16 + (s >> 4);
    int gp0 = n * 2048 + (s & 15) * 128 + w * 32;

#pragma unroll 1
    for (int rep = 0; rep < SFREP; ++rep) {
        float xm[2], ym[2];
#pragma unroll
        for (int m = 0; m < 2; ++m) {
            int gp = gp0 + m * 16 + lr;
            xm[m] = xs[gp]; ym[m] = ys[gp];
        }
        f32x4 acc[2][8];
#pragma unroll
        for (int nj = 0; nj < 8; ++nj) {
            float bv = b0[nj * 16 + lr];
            acc[0][nj] = (f32x4){bv, bv, bv, bv};
            acc[1][nj] = acc[0][nj];
        }
#pragma unroll
        for (int ks = 0; ks < 4; ++ks) {
            int f0 = ks * 32 + lg * 8;
            f32x4 B0a = *(const f32x4*)&Bm[f0];
            f32x4 B0b = *(const f32x4*)&Bm[f0 + 4];
            f32x4 B1a = *(const f32x4*)&Bm[128 + f0];
            f32x4 B1b = *(const f32x4*)&Bm[128 + f0 + 4];
            short8 asn[2], acs[2];
#pragma unroll
            for (int m = 0; m < 2; ++m) {
                float t_[8];
#pragma unroll
                for (int jj = 0; jj < 4; ++jj) {
                    t_[jj]     = xm[m] * B0a[jj] + ym[m] * B1a[jj];
                    t_[4 + jj] = xm[m] * B0b[jj] + ym[m] * B1b[jj];
                }
#pragma unroll
                for (int jj = 0; jj < 8; ++jj) {
                    float tf = t_[jj] - floorf(t_[jj]);
                    float sv, cv;
                    asm("v_sin_f32 %0, %1" : "=v"(sv) : "v"(tf));
                    asm("v_cos_f32 %0, %1" : "=v"(cv) : "v"(tf));
                    asn[m][jj] = (short)f2b(sv);
                    acs[m][jj] = (short)f2b(cv);
                }
            }
#pragma unroll
            for (int nj = 0; nj < 8; ++nj) {
                short8 bs = *(const short8*)&w0ft[(nj * 16 + lr) * 256 + ks * 32 + lg * 8];
                acc[0][nj] = MFMA_BF16(asn[0], bs, acc[0][nj], 0, 0, 0);
                acc[1][nj] = MFMA_BF16(asn[1], bs, acc[1][nj], 0, 0, 0);
            }
#pragma unroll
            for (int nj = 0; nj < 8; ++nj) {
                short8 bc = *(const short8*)&w0ft[(nj * 16 + lr) * 256 + (4 + ks) * 32 + lg * 8];
                acc[0][nj] = MFMA_BF16(acs[0], bc, acc[0][nj], 0, 0, 0);
                acc[1][nj] = MFMA_BF16(acs[1], bc, acc[1][nj], 0, 0, 0);
            }
        }
#pragma unroll
        for (int m = 0; m < 2; ++m) {
#pragma unroll
            for (int nj = 0; nj < 8; ++nj)
#pragma unroll
                for (int r4 = 0; r4 < 4; ++r4)
                    hb[w][lg * 4 + r4][nj * 16 + lr] = f2b(acc[m][nj][r4]);
            asm volatile("s_waitcnt lgkmcnt(0)" ::: "memory");
            us4* df = (us4*)(F + (size_t)(gp0 + m * 16) * 128);
#pragma unroll
            for (int it = 0; it < 8; ++it) {
                int idx = lane + it * 64;
                int px = idx >> 5, c4 = idx & 31;
                df[px * 32 + c4] = *(us4*)&hb[w][px][c4 * 4];
            }
            asm volatile("s_waitcnt lgkmcnt(0)" ::: "memory");
        }
    }
}

// ---------------------------------------------------------------------------
// R11 K2': decoder, rep=4. LAST launch -> defines d_out.
// ---------------------------------------------------------------------------
#define DREP 4
__global__ __launch_bounds__(256, 3) void decoder(
    const unsigned short* __restrict__ P, const unsigned short* __restrict__ F,
    const float* __restrict__ xs, const float* __restrict__ ys,
    const unsigned short* __restrict__ w1t, const float* __restrict__ b1,
    const unsigned short* __restrict__ w2p, const float* __restrict__ b2,
    float* __restrict__ out) {
    __shared__ unsigned short w1s[128][136];
    __shared__ unsigned short hb[4][16][136];
    int tid = threadIdx.x, lane = tid & 63, w = tid >> 6;
    int lr = lane & 15, lg = lane >> 4;
    {
        const short8* s1 = (const short8*)w1t;
#pragma unroll
        for (int it = 0; it < 8; ++it) {
            int c = tid + it * 256;
            int row = c >> 4, cc = c & 15;
            *(short8*)&w1s[row][cc * 8] = s1[c];
        }
    }
    __syncthreads();

    int bid = blockIdx.x;
    int x = bid & 7, s = bid >> 3;
    int n = x * 16 + (s >> 4);
    int gp0 = n * 2048 + (s & 15) * 128 + w * 32;
    const char* base = (const char*)P + ((size_t)n << 20) + lg * 16;

#pragma unroll 1
    for (int rep = 0; rep < DREP; ++rep) {
        float wxv[2], wyv[2];
        int o00[2], o01[2], o10[2], o11[2];
#pragma unroll
        for (int m = 0; m < 2; ++m) {
            int gp = gp0 + m * 16 + lr;
            float xc = xs[gp], yc = ys[gp];
            float px = xc * 63.f, py = yc * 63.f;
            float x0f = fminf(fmaxf(floorf(px), 0.f), 63.f);
            float y0f = fminf(fmaxf(floorf(py), 0.f), 63.f);
            wxv[m] = px - x0f; wyv[m] = py - y0f;
            int xi0 = (int)x0f, yi0 = (int)y0f;
            int xi1 = min(xi0 + 1, 63), yi1 = min(yi0 + 1, 63);
            o00[m] = (yi0 * 64 + xi0) * 256;
            o01[m] = (yi0 * 64 + xi1) * 256;
            o10[m] = (yi1 * 64 + xi0) * 256;
            o11[m] = (yi1 * 64 + xi1) * 256;
        }

        short8 a1[2][4];
#pragma unroll
        for (int m = 0; m < 2; ++m) {
            float wx = wxv[m], wy = wyv[m];
            float ivx = 1.f - wx, ivy = 1.f - wy;
            const unsigned short* fr = F + (size_t)(gp0 + m * 16 + lr) * 128 + lg * 8;
#pragma unroll
            for (int q = 0; q < 4; ++q) {
                short8 c00 = *(const short8*)(base + o00[m] + q * 64);
                short8 c01 = *(const short8*)(base + o01[m] + q * 64);
                short8 c10 = *(const short8*)(base + o10[m] + q * 64);
                short8 c11 = *(const short8*)(base + o11[m] + q * 64);
                short8 f8  = *(const short8*)(fr + q * 32);
#pragma unroll
                for (int jj = 0; jj < 8; ++jj) {
                    float top = b2f((unsigned short)c00[jj]) * ivx + b2f((unsigned short)c01[jj]) * wx;
                    float bot = b2f((unsigned short)c10[jj]) * ivx + b2f((unsigned short)c11[jj]) * wx;
                    float v = top * ivy + bot * wy + b2f((unsigned short)f8[jj]);
                    a1[m][q][jj] = (short)f2b(fmaxf(v, 0.f));
                }
            }
        }

        f32x4 acc[2][8];
#pragma unroll
        for (int nj = 0; nj < 8; ++nj) {
            float bv = b1[nj * 16 + lr];
            acc[0][nj] = (f32x4){bv, bv, bv, bv};
            acc[1][nj] = acc[0][nj];
        }
#pragma unroll
        for (int ks = 0; ks < 4; ++ks)
#pragma unroll
            for (int nj = 0; nj < 8; ++nj) {
                short8 b = *(const short8*)&w1s[nj * 16 + lr][ks * 32 + lg * 8];
                acc[0][nj] = MFMA_BF16(a1[0][ks], b, acc[0][nj], 0, 0, 0);
                acc[1][nj] = MFMA_BF16(a1[1][ks], b, acc[1][nj], 0, 0, 0);
            }

        float bb2 = (lr < 2) ? b2[lr] : 0.f;
#pragma unroll
        for (int m = 0; m < 2; ++m) {
#pragma unroll
            for (int nj = 0; nj < 8; ++nj)
#pragma unroll
                for (int r4 = 0; r4 < 4; ++r4)
                    hb[w][lg * 4 + r4][nj * 16 + lr] = f2b(fmaxf(acc[m][nj][r4], 0.f));
            asm volatile("s_waitcnt lgkmcnt(0)" ::: "memory");
            f32x4 acc2 = (f32x4){bb2, bb2, bb2, bb2};
#pragma unroll
            for (int ks = 0; ks < 4; ++ks) {
                short8 a2 = *(const short8*)&hb[w][lr][ks * 32 + lg * 8];
                short8 bz = *(const short8*)&w2p[lr * 128 + ks * 32 + lg * 8];
                acc2 = MFMA_BF16(a2, bz, acc2, 0, 0, 0);
            }
            asm volatile("s_waitcnt lgkmcnt(0)" ::: "memory");
            if (lr < 2) {
#pragma unroll
                for (int r4 = 0; r4 < 4; ++r4) {
                    int gpo = gp0 + m * 16 + lg * 4 + r4;
                    float v = acc2[r4];
                    if (lr == 0) {
                        out[gpo * 2] = v;
                    } else {
                        float sp = (v > 20.f) ? v : log1pf(expf(v));
                        out[gpo * 2 + 1] = sp + 0.01f;
                    }
                }
            }
        }
    }
}

// ---------------------------------------------------------------------------
extern "C" void kernel_launch(void* const* d_in, const int* in_sizes, int n_in,
                              void* d_out, int out_size, void* d_ws, size_t ws_size,
                              hipStream_t stream) {
    const float* h_grid = (const float*)d_in[0];
    const float* xs = (const float*)d_in[1];
    const float* ys = (const float*)d_in[2];
    const float* Bm = (const float*)d_in[3];
    const float* W0 = (const float*)d_in[4];
    const float* b0 = (const float*)d_in[5];
    const float* W1 = (const float*)d_in[6];
    const float* b1 = (const float*)d_in[7];
    const float* W2 = (const float*)d_in[8];
    const float* b2 = (const float*)d_in[9];
    float* out = (float*)d_out;

    // ws carve
    unsigned short* ht   = (unsigned short*)d_ws;
    unsigned short* P    = (unsigned short*)((char*)d_ws + 134217728ull);
    unsigned short* F    = (unsigned short*)((char*)d_ws + 268435456ull);
    unsigned short* w0t  = (unsigned short*)((char*)d_ws + 335544320ull);
    unsigned short* w0st = w0t + 128 * 384;
    unsigned short* w0ft = w0st + 128 * 128;
    unsigned short* w1t  = w0ft + 128 * 256;
    unsigned short* w2p  = w1t + 128 * 128;

    transpose_h<<<dim3(8192), dim3(256), 0, stream>>>(h_grid, ht);
    prep_weights<<<dim3(64), dim3(256), 0, stream>>>(W0, W1, W2, w0t, w0st, w0ft, w1t, w2p);
    fused_decoder<<<dim3(1024), dim3(512), 0, stream>>>(ht, xs, ys, Bm, w0t, b0, w1t, b1, w2p, b2, out);
    proj_h<<<dim3(8192), dim3(256), 0, stream>>>(h_grid, w0st, P);
    spatial_F<<<dim3(2048), dim3(256), 0, stream>>>(xs, ys, Bm, w0ft, b0, F);
    decoder<<<dim3(2048), dim3(256), 0, stream>>>(P, F, xs, ys, w1t, b1, w2p, b2, out);
}

// Round 13
// 415.617 us; speedup vs baseline: 3.0769x; 3.0769x over previous
//
#include <hip/hip_runtime.h>
#include <hip/hip_bf16.h>
#include <math.h>

typedef __attribute__((ext_vector_type(8))) short short8;
typedef __attribute__((ext_vector_type(4))) float f32x4;
typedef __attribute__((ext_vector_type(4))) unsigned short us4;

#define MFMA_BF16 __builtin_amdgcn_mfma_f32_16x16x32_bf16

__device__ __forceinline__ float b2f(unsigned short u) {
    union { unsigned int i; float f; } v; v.i = ((unsigned int)u) << 16; return v.f;
}
__device__ __forceinline__ unsigned short f2b(float f) {
    __hip_bfloat16 h = __float2bfloat16(f);
    return *reinterpret_cast<unsigned short*>(&h);
}

// ---------------------------------------------------------------------------
// prep: weight layouts (w0 sampled/fourier transposed, w1t, padded w2)
// ---------------------------------------------------------------------------
__global__ void prep_weights(const float* __restrict__ W0, const float* __restrict__ W1,
                             const float* __restrict__ W2,
                             unsigned short* __restrict__ w0st, unsigned short* __restrict__ w0ft,
                             unsigned short* __restrict__ w1t,  unsigned short* __restrict__ w2p) {
    int i = blockIdx.x * 256 + threadIdx.x;
    for (int idx = i; idx < 128 * 128; idx += gridDim.x * 256) {
        int j = idx >> 7, k = idx & 127;
        w0st[idx] = f2b(W0[k * 128 + j]);
    }
    for (int idx = i; idx < 128 * 256; idx += gridDim.x * 256) {
        int j = idx >> 8, k = idx & 255;
        w0ft[idx] = f2b(W0[(128 + k) * 128 + j]);
    }
    for (int idx = i; idx < 128 * 128; idx += gridDim.x * 256) {
        int j = idx >> 7, k = idx & 127;
        w1t[idx] = f2b(W1[k * 128 + j]);
    }
    for (int idx = i; idx < 16 * 128; idx += gridDim.x * 256) {
        int r = idx >> 7, k = idx & 127;
        w2p[idx] = (r < 2) ? f2b(W2[k * 2 + r]) : (unsigned short)0;
    }
}

// ---------------------------------------------------------------------------
// K0': transpose+project, DESTAGED: w0st B-frags from global (L2-hot).
// LDS only t[128][65] (33 KB) -> 4 blocks/CU. NT store for P.
// ---------------------------------------------------------------------------
__global__ __launch_bounds__(256, 4) void proj_h(const float* __restrict__ hg,
                                                 const unsigned short* __restrict__ w0st,
                                                 unsigned short* __restrict__ P) {
    __shared__ float t[128][65];
    int bid = blockIdx.x;                        // 8192 = 8 xcd * 16 img * 64 strips
    int x = bid & 7, r = bid >> 3;
    int n = x * 16 + (r & 15);
    int pb = r >> 4;
    int tid = threadIdx.x;
    const float* src = hg + (size_t)n * 128 * 4096 + pb * 64;
    int j = tid & 63, i0 = tid >> 6;
#pragma unroll
    for (int ii = 0; ii < 32; ++ii) {
        int ch = ii * 4 + i0;
        t[ch][j] = src[(size_t)ch * 4096 + j];
    }
    __syncthreads();

    int lane = tid & 63, w = tid >> 6, lr = lane & 15, lg = lane >> 4;
    short8 afr[4];
#pragma unroll
    for (int ks = 0; ks < 4; ++ks) {
        int px = w * 16 + lr;
#pragma unroll
        for (int jj = 0; jj < 8; ++jj)
            afr[ks][jj] = (short)f2b(t[ks * 32 + lg * 8 + jj][px]);
    }
    __syncthreads();                             // t reusable as bounce

    f32x4 acc[8];
#pragma unroll
    for (int nj = 0; nj < 8; ++nj) acc[nj] = (f32x4){0.f, 0.f, 0.f, 0.f};
#pragma unroll
    for (int ks = 0; ks < 4; ++ks)
#pragma unroll
        for (int nj = 0; nj < 8; ++nj) {
            short8 b = *(const short8*)&w0st[(nj * 16 + lr) * 128 + ks * 32 + lg * 8];
            acc[nj] = MFMA_BF16(afr[ks], b, acc[nj], 0, 0, 0);
        }

    unsigned short* tb = (unsigned short*)t;     // [64][136]
#pragma unroll
    for (int nj = 0; nj < 8; ++nj)
#pragma unroll
        for (int r4 = 0; r4 < 4; ++r4)
            tb[(w * 16 + lg * 4 + r4) * 136 + nj * 16 + lr] = f2b(acc[nj][r4]);
    __syncthreads();
    us4* dst = (us4*)(P + ((size_t)n * 4096 + pb * 64) * 128);
#pragma unroll
    for (int it = 0; it < 8; ++it) {
        int idx = tid + it * 256;
        int px = idx >> 5, c4 = idx & 31;
        __builtin_nontemporal_store(*(us4*)&tb[px * 136 + c4 * 4], &dst[px * 32 + c4]);
    }
}

// ---------------------------------------------------------------------------
// K1': F = spatial . W0f + b0, per-m split (acc 32 AGPR). NT stores for F.
// w0ft streamed from global (stays L2-hot now that F doesn't pollute).
// ---------------------------------------------------------------------------
__global__ __launch_bounds__(256, 3) void spatial_F(
    const float* __restrict__ xs, const float* __restrict__ ys,
    const float* __restrict__ Bm, const unsigned short* __restrict__ w0ft,
    const float* __restrict__ b0, unsigned short* __restrict__ F) {
    __shared__ unsigned short hb[4][16][136];    // 17.4 KB
    int tid = threadIdx.x, lane = tid & 63, w = tid >> 6;
    int lr = lane & 15, lg = lane >> 4;
    int bid = blockIdx.x;                        // 2048 = 8 xcd * 16 img * 16 tiles
    int x = bid & 7, s = bid >> 3;
    int n = x * 16 + (s >> 4);
    int gp0 = n * 2048 + (s & 15) * 128 + w * 32;

#pragma unroll
    for (int m = 0; m < 2; ++m) {
        int gp = gp0 + m * 16 + lr;
        float xc = xs[gp], yc = ys[gp];

        // trig for all 4 k-slices of this m (cover for B loads)
        short8 asn[4], acs[4];
#pragma unroll
        for (int ks = 0; ks < 4; ++ks) {
            int f0 = ks * 32 + lg * 8;
            f32x4 B0a = *(const f32x4*)&Bm[f0];
            f32x4 B0b = *(const f32x4*)&Bm[f0 + 4];
            f32x4 B1a = *(const f32x4*)&Bm[128 + f0];
            f32x4 B1b = *(const f32x4*)&Bm[128 + f0 + 4];
            float t_[8];
#pragma unroll
            for (int jj = 0; jj < 4; ++jj) {
                t_[jj]     = xc * B0a[jj] + yc * B1a[jj];
                t_[4 + jj] = xc * B0b[jj] + yc * B1b[jj];
            }
#pragma unroll
            for (int jj = 0; jj < 8; ++jj) {
                float tf = t_[jj] - floorf(t_[jj]);   // revolutions for HW trig
                float sv, cv;
                asm("v_sin_f32 %0, %1" : "=v"(sv) : "v"(tf));
                asm("v_cos_f32 %0, %1" : "=v"(cv) : "v"(tf));
                asn[ks][jj] = (short)f2b(sv);
                acs[ks][jj] = (short)f2b(cv);
            }
        }

        f32x4 acc[8];
#pragma unroll
        for (int nj = 0; nj < 8; ++nj) {
            float bv = b0[nj * 16 + lr];
            acc[nj] = (f32x4){bv, bv, bv, bv};
        }
#pragma unroll
        for (int ks = 0; ks < 4; ++ks) {
#pragma unroll
            for (int nj = 0; nj < 8; ++nj) {
                short8 bs = *(const short8*)&w0ft[(nj * 16 + lr) * 256 + ks * 32 + lg * 8];
                acc[nj] = MFMA_BF16(asn[ks], bs, acc[nj], 0, 0, 0);
            }
#pragma unroll
            for (int nj = 0; nj < 8; ++nj) {
                short8 bc = *(const short8*)&w0ft[(nj * 16 + lr) * 256 + (4 + ks) * 32 + lg * 8];
                acc[nj] = MFMA_BF16(acs[ks], bc, acc[nj], 0, 0, 0);
            }
        }

        // bounce D -> row-major, NT store (pre-activation)
#pragma unroll
        for (int nj = 0; nj < 8; ++nj)
#pragma unroll
            for (int r4 = 0; r4 < 4; ++r4)
                hb[w][lg * 4 + r4][nj * 16 + lr] = f2b(acc[nj][r4]);
        asm volatile("s_waitcnt lgkmcnt(0)" ::: "memory");
        us4* df = (us4*)(F + (size_t)(gp0 + m * 16) * 128);
#pragma unroll
        for (int it = 0; it < 8; ++it) {
            int idx = lane + it * 64;
            int px = idx >> 5, c4 = idx & 31;
            __builtin_nontemporal_store(*(us4*)&hb[w][px][c4 * 4], &df[px * 32 + c4]);
        }
        asm volatile("s_waitcnt lgkmcnt(0)" ::: "memory");
    }
}

// ---------------------------------------------------------------------------
// K2': decoder, per-m full pipeline (acc[8] only, ~110 regs -> 4 waves/SIMD).
// W1 streamed from global (L2-hot), F via NT loads, LDS only hb (17 KB).
// ---------------------------------------------------------------------------
__global__ __launch_bounds__(256, 4) void decoder(
    const unsigned short* __restrict__ P, const unsigned short* __restrict__ F,
    const float* __restrict__ xs, const float* __restrict__ ys,
    const unsigned short* __restrict__ w1t, const float* __restrict__ b1,
    const unsigned short* __restrict__ w2p, const float* __restrict__ b2,
    float* __restrict__ out) {
    __shared__ unsigned short hb[4][16][136];    // 17.4 KB
    int tid = threadIdx.x, lane = tid & 63, w = tid >> 6;
    int lr = lane & 15, lg = lane >> 4;

    int bid = blockIdx.x;                        // 2048 = 8 xcd * 16 img * 16 tiles
    int x = bid & 7, s = bid >> 3;
    int n = x * 16 + (s >> 4);
    int gp0 = n * 2048 + (s & 15) * 128 + w * 32;
    const char* base = (const char*)P + ((size_t)n << 20) + lg * 16;
    float bb2 = (lr < 2) ? b2[lr] : 0.f;

#pragma unroll
    for (int m = 0; m < 2; ++m) {
        int gp = gp0 + m * 16 + lr;
        float xc = xs[gp], yc = ys[gp];
        float px = xc * 63.f, py = yc * 63.f;
        float x0f = fminf(fmaxf(floorf(px), 0.f), 63.f);
        float y0f = fminf(fmaxf(floorf(py), 0.f), 63.f);
        float wx = px - x0f, wy = py - y0f;
        float ivx = 1.f - wx, ivy = 1.f - wy;
        int xi0 = (int)x0f, yi0 = (int)y0f;
        int xi1 = min(xi0 + 1, 63), yi1 = min(yi0 + 1, 63);
        int o00 = (yi0 * 64 + xi0) * 256, o01 = (yi0 * 64 + xi1) * 256;
        int o10 = (yi1 * 64 + xi0) * 256, o11 = (yi1 * 64 + xi1) * 256;
        const unsigned short* fr = F + (size_t)gp * 128 + lg * 8;

        // layer 0 = lerp(P) + F -> A-frags directly
        short8 a1[4];
#pragma unroll
        for (int q = 0; q < 4; ++q) {
            short8 c00 = *(const short8*)(base + o00 + q * 64);
            short8 c01 = *(const short8*)(base + o01 + q * 64);
            short8 c10 = *(const short8*)(base + o10 + q * 64);
            short8 c11 = *(const short8*)(base + o11 + q * 64);
            short8 f8  = __builtin_nontemporal_load((const short8*)(fr + q * 32));
#pragma unroll
            for (int jj = 0; jj < 8; ++jj) {
                float top = b2f((unsigned short)c00[jj]) * ivx + b2f((unsigned short)c01[jj]) * wx;
                float bot = b2f((unsigned short)c10[jj]) * ivx + b2f((unsigned short)c11[jj]) * wx;
                float v = top * ivy + bot * wy + b2f((unsigned short)f8[jj]);
                a1[q][jj] = (short)f2b(fmaxf(v, 0.f));
            }
        }

        // layer 1
        f32x4 acc[8];
#pragma unroll
        for (int nj = 0; nj < 8; ++nj) {
            float bv = b1[nj * 16 + lr];
            acc[nj] = (f32x4){bv, bv, bv, bv};
        }
#pragma unroll
        for (int ks = 0; ks < 4; ++ks)
#pragma unroll
            for (int nj = 0; nj < 8; ++nj) {
                short8 b = *(const short8*)&w1t[(nj * 16 + lr) * 128 + ks * 32 + lg * 8];
                acc[nj] = MFMA_BF16(a1[ks], b, acc[nj], 0, 0, 0);
            }

        // layer 2 via hb bounce
#pragma unroll
        for (int nj = 0; nj < 8; ++nj)
#pragma unroll
            for (int r4 = 0; r4 < 4; ++r4)
                hb[w][lg * 4 + r4][nj * 16 + lr] = f2b(fmaxf(acc[nj][r4], 0.f));
        asm volatile("s_waitcnt lgkmcnt(0)" ::: "memory");
        f32x4 acc2 = (f32x4){bb2, bb2, bb2, bb2};
#pragma unroll
        for (int ks = 0; ks < 4; ++ks) {
            short8 a2 = *(const short8*)&hb[w][lr][ks * 32 + lg * 8];
            short8 bz = *(const short8*)&w2p[lr * 128 + ks * 32 + lg * 8];
            acc2 = MFMA_BF16(a2, bz, acc2, 0, 0, 0);
        }
        asm volatile("s_waitcnt lgkmcnt(0)" ::: "memory");
        if (lr < 2) {
#pragma unroll
            for (int r4 = 0; r4 < 4; ++r4) {
                int gpo = gp0 + m * 16 + lg * 4 + r4;
                float v = acc2[r4];
                if (lr == 0) {
                    out[gpo * 2] = v;
                } else {
                    float sp = (v > 20.f) ? v : log1pf(expf(v));
                    out[gpo * 2 + 1] = sp + 0.01f;
                }
            }
        }
    }
}

// ---------------------------------------------------------------------------
extern "C" void kernel_launch(void* const* d_in, const int* in_sizes, int n_in,
                              void* d_out, int out_size, void* d_ws, size_t ws_size,
                              hipStream_t stream) {
    const float* h_grid = (const float*)d_in[0];
    const float* xs = (const float*)d_in[1];
    const float* ys = (const float*)d_in[2];
    const float* Bm = (const float*)d_in[3];
    const float* W0 = (const float*)d_in[4];
    const float* b0 = (const float*)d_in[5];
    const float* W1 = (const float*)d_in[6];
    const float* b1 = (const float*)d_in[7];
    const float* W2 = (const float*)d_in[8];
    const float* b2 = (const float*)d_in[9];
    float* out = (float*)d_out;

    // ws carve: P 134217728 | F 67108864 | weights
    unsigned short* P    = (unsigned short*)d_ws;
    unsigned short* F    = (unsigned short*)((char*)d_ws + 134217728ull);
    unsigned short* w0st = (unsigned short*)((char*)d_ws + 134217728ull + 67108864ull);
    unsigned short* w0ft = w0st + 128 * 128;
    unsigned short* w1t  = w0ft + 128 * 256;
    unsigned short* w2p  = w1t + 128 * 128;

    prep_weights<<<dim3(64), dim3(256), 0, stream>>>(W0, W1, W2, w0st, w0ft, w1t, w2p);
    proj_h<<<dim3(8192), dim3(256), 0, stream>>>(h_grid, w0st, P);
    spatial_F<<<dim3(2048), dim3(256), 0, stream>>>(xs, ys, Bm, w0ft, b0, F);
    decoder<<<dim3(2048), dim3(256), 0, stream>>>(P, F, xs, ys, w1t, b1, w2p, b2, out);
}

// Round 14
// 240.384 us; speedup vs baseline: 5.3199x; 1.7290x over previous
//
#include <hip/hip_runtime.h>
#include <hip/hip_bf16.h>
#include <math.h>

typedef __attribute__((ext_vector_type(8))) short short8;
typedef __attribute__((ext_vector_type(4))) float f32x4;
typedef __attribute__((ext_vector_type(4))) unsigned short us4;

#define MFMA_BF16 __builtin_amdgcn_mfma_f32_16x16x32_bf16

__device__ __forceinline__ float b2f(unsigned short u) {
    union { unsigned int i; float f; } v; v.i = ((unsigned int)u) << 16; return v.f;
}
__device__ __forceinline__ unsigned short f2b(float f) {
    __hip_bfloat16 h = __float2bfloat16(f);
    return *reinterpret_cast<unsigned short*>(&h);
}

// ---------------------------------------------------------------------------
// K0: h_grid (128,128ch,64x64) fp32 -> ht (128,4096px,128ch) bf16  (~50us)
// ---------------------------------------------------------------------------
__global__ __launch_bounds__(256) void transpose_h(const float* __restrict__ hg,
                                                   unsigned short* __restrict__ ht) {
    __shared__ float t[128][65];
    int bid = blockIdx.x;                        // 8192 = 8 xcd * 1024
    int x = bid & 7, r = bid >> 3;
    int n = x * 16 + (r & 15);                   // image pinned to xcd
    int pb = r >> 4;
    int tid = threadIdx.x;
    const float* src = hg + (size_t)n * 128 * 4096 + pb * 64;
    int j = tid & 63, i0 = tid >> 6;
#pragma unroll
    for (int ii = 0; ii < 32; ++ii) {
        int ch = ii * 4 + i0;
        t[ch][j] = src[(size_t)ch * 4096 + j];
    }
    __syncthreads();
#pragma unroll
    for (int it = 0; it < 8; ++it) {
        int idx = tid + it * 256;
        int px = idx >> 5, cq = idx & 31;
        us4 o;
#pragma unroll
        for (int rr = 0; rr < 4; ++rr) o[rr] = f2b(t[cq * 4 + rr][px]);
        *(us4*)&ht[((size_t)n * 4096 + pb * 64 + px) * 128 + cq * 4] = o;
    }
}

// ---------------------------------------------------------------------------
// K1: weights -> transposed bf16 + padded W2 strip
// ---------------------------------------------------------------------------
__global__ void prep_weights(const float* __restrict__ W0, const float* __restrict__ W1,
                             const float* __restrict__ W2,
                             unsigned short* __restrict__ w0t, unsigned short* __restrict__ w1t,
                             unsigned short* __restrict__ w2p) {
    int i = blockIdx.x * 256 + threadIdx.x;
    for (int idx = i; idx < 128 * 384; idx += gridDim.x * 256) {
        int j = idx / 384, k = idx - j * 384;
        w0t[idx] = f2b(W0[k * 128 + j]);
    }
    for (int idx = i; idx < 128 * 128; idx += gridDim.x * 256) {
        int j = idx >> 7, k = idx & 127;
        w1t[idx] = f2b(W1[k * 128 + j]);
    }
    for (int idx = i; idx < 16 * 128; idx += gridDim.x * 256) {
        int r = idx >> 7, k = idx & 127;
        w2p[idx] = (r < 2) ? f2b(W2[k * 2 + r]) : (unsigned short)0;
    }
}

// ---------------------------------------------------------------------------
// K2: fused, R7 schedule with m=1 (16 pts/wave) to kill the spill.
// 512 thr (8 waves), grid 2048. W0 in LDS, 784B pitch (conflict-free b128).
// Dual corner sets (A=even, B=odd slices), prefetched 2 slices deep.
// ---------------------------------------------------------------------------
#define W0P 784
#define HBP 272

__global__ __launch_bounds__(512, 2) void fused_decoder(
    const unsigned short* __restrict__ ht,
    const float* __restrict__ xs, const float* __restrict__ ys,
    const float* __restrict__ Bm,
    const unsigned short* __restrict__ w0t, const float* __restrict__ b0,
    const unsigned short* __restrict__ w1t, const float* __restrict__ b1,
    const unsigned short* __restrict__ w2p, const float* __restrict__ b2,
    float* __restrict__ out)
{
    __shared__ char smem[128 * W0P + 8 * 16 * HBP];   // 135168 B
    char* w0s = smem;
    int tid = threadIdx.x, lane = tid & 63, w = tid >> 6;
    int lr = lane & 15, lg = lane >> 4;
    char* hb = smem + 128 * W0P + w * 16 * HBP;

    // ---- stage W0 into LDS, 784B pitch
    {
        const short8* src = (const short8*)w0t;
#pragma unroll 1
        for (int it = 0; it < 12; ++it) {
            int c = tid + it * 512;
            int row = c / 48, cc = c - row * 48;
            *(short8*)(w0s + row * W0P + cc * 16) = src[c];
        }
    }
    __syncthreads();

    int bid = blockIdx.x;                 // 2048 = 8 xcd * 256
    int x = bid & 7, s = bid >> 3;
    int n = x * 16 + (s >> 4);            // image 0..127 (same xcd as transpose)
    int pt = s & 15;                      // 128-pt tile
    int gp0 = n * 2048 + pt * 128 + w * 16;
    int gp = gp0 + lr;

    // ---- per-lane coords
    float xc = xs[gp], yc = ys[gp];
    float px = xc * 63.f, py = yc * 63.f;
    float x0f = fminf(fmaxf(floorf(px), 0.f), 63.f);
    float y0f = fminf(fmaxf(floorf(py), 0.f), 63.f);
    float wx = px - x0f, wy = py - y0f;
    float ivx = 1.f - wx, ivy = 1.f - wy;
    int xi0 = (int)x0f, yi0 = (int)y0f;
    int xi1 = min(xi0 + 1, 63), yi1 = min(yi0 + 1, 63);
    int o00 = (yi0 * 64 + xi0) * 256, o01 = (yi0 * 64 + xi1) * 256;
    int o10 = (yi1 * 64 + xi0) * 256, o11 = (yi1 * 64 + xi1) * 256;
    const char* base = (const char*)ht + ((size_t)n << 20) + lg * 16;

    // ================= layer 0 =================
    f32x4 acc[8];
#pragma unroll
    for (int nj = 0; nj < 8; ++nj) {
        float bv = b0[nj * 16 + lr];
        acc[nj] = (f32x4){bv, bv, bv, bv};
    }

    short8 A00, A01, A10, A11;            // even slices
    short8 B00, B01, B10, B11;            // odd slices
    A00 = *(const short8*)(base + o00);
    A01 = *(const short8*)(base + o01);
    A10 = *(const short8*)(base + o10);
    A11 = *(const short8*)(base + o11);
    B00 = *(const short8*)(base + o00 + 64);
    B01 = *(const short8*)(base + o01 + 64);
    B10 = *(const short8*)(base + o10 + 64);
    B11 = *(const short8*)(base + o11 + 64);

#pragma unroll 1
    for (int s2 = 0; s2 < 2; ++s2) {
#pragma unroll
        for (int half = 0; half < 2; ++half) {
            int q = 2 * s2 + half;
            // ---- fourier slice q (VALU cover for in-flight corner loads)
            short8 asn, acs;
            {
                int f0 = q * 32 + lg * 8;
                f32x4 B0a = *(const f32x4*)&Bm[f0];
                f32x4 B0b = *(const f32x4*)&Bm[f0 + 4];
                f32x4 B1a = *(const f32x4*)&Bm[128 + f0];
                f32x4 B1b = *(const f32x4*)&Bm[128 + f0 + 4];
                float t_[8];
#pragma unroll
                for (int jj = 0; jj < 4; ++jj) {
                    t_[jj]     = xc * B0a[jj] + yc * B1a[jj];
                    t_[4 + jj] = xc * B0b[jj] + yc * B1b[jj];
                }
#pragma unroll
                for (int jj = 0; jj < 8; ++jj) {
                    float tf = t_[jj] - floorf(t_[jj]);   // revolutions for HW trig
                    float sv, cv;
                    asm("v_sin_f32 %0, %1" : "=v"(sv) : "v"(tf));
                    asm("v_cos_f32 %0, %1" : "=v"(cv) : "v"(tf));
                    asn[jj] = (short)f2b(sv);
                    acs[jj] = (short)f2b(cv);
                }
            }
#pragma unroll
            for (int nj = 0; nj < 8; ++nj) {
                short8 bs = *(const short8*)(w0s + (nj * 16 + lr) * W0P + (4 + q) * 64 + lg * 16);
                acc[nj] = MFMA_BF16(asn, bs, acc[nj], 0, 0, 0);
            }
#pragma unroll
            for (int nj = 0; nj < 8; ++nj) {
                short8 bc = *(const short8*)(w0s + (nj * 16 + lr) * W0P + (8 + q) * 64 + lg * 16);
                acc[nj] = MFMA_BF16(acs, bc, acc[nj], 0, 0, 0);
            }
            // ---- lerp slice q from its set, reload that set 2 slices ahead
            short8 a;
            {
                short8 c0 = half ? B00 : A00, c1 = half ? B01 : A01;
                short8 c2 = half ? B10 : A10, c3 = half ? B11 : A11;
#pragma unroll
                for (int jj = 0; jj < 8; ++jj) {
                    float top = b2f((unsigned short)c0[jj]) * ivx + b2f((unsigned short)c1[jj]) * wx;
                    float bot = b2f((unsigned short)c2[jj]) * ivx + b2f((unsigned short)c3[jj]) * wx;
                    a[jj] = (short)f2b(top * ivy + bot * wy);
                }
            }
            if (s2 == 0) {
                int so = (q + 2) * 64;
                if (half == 0) {
                    A00 = *(const short8*)(base + o00 + so);
                    A01 = *(const short8*)(base + o01 + so);
                    A10 = *(const short8*)(base + o10 + so);
                    A11 = *(const short8*)(base + o11 + so);
                } else {
                    B00 = *(const short8*)(base + o00 + so);
                    B01 = *(const short8*)(base + o01 + so);
                    B10 = *(const short8*)(base + o10 + so);
                    B11 = *(const short8*)(base + o11 + so);
                }
            }
#pragma unroll
            for (int nj = 0; nj < 8; ++nj) {
                short8 b = *(const short8*)(w0s + (nj * 16 + lr) * W0P + q * 64 + lg * 16);
                acc[nj] = MFMA_BF16(a, b, acc[nj], 0, 0, 0);
            }
        }
    }

    // ================= layer 1: h0(16x128) @ W1(128x128) =================
#pragma unroll
    for (int nj = 0; nj < 8; ++nj)
#pragma unroll
        for (int r = 0; r < 4; ++r) {
            int row = lg * 4 + r;
            *(unsigned short*)(hb + row * HBP + (nj * 16 + lr) * 2) =
                f2b(fmaxf(acc[nj][r], 0.f));
        }
    asm volatile("s_waitcnt lgkmcnt(0)" ::: "memory");
    short8 a1[4];
#pragma unroll
    for (int ks = 0; ks < 4; ++ks)
        a1[ks] = *(const short8*)(hb + lr * HBP + ks * 64 + lg * 16);
    asm volatile("s_waitcnt lgkmcnt(0)" ::: "memory");

#pragma unroll
    for (int nj = 0; nj < 8; ++nj) {
        float bv = b1[nj * 16 + lr];
        acc[nj] = (f32x4){bv, bv, bv, bv};
    }
#pragma unroll
    for (int ks = 0; ks < 4; ++ks)
#pragma unroll
        for (int nj = 0; nj < 8; ++nj) {
            short8 b = *(const short8*)&w1t[(nj * 16 + lr) * 128 + ks * 32 + lg * 8];
            acc[nj] = MFMA_BF16(a1[ks], b, acc[nj], 0, 0, 0);
        }

    // ================= layer 2: h1 @ W2p =================
#pragma unroll
    for (int nj = 0; nj < 8; ++nj)
#pragma unroll
        for (int r = 0; r < 4; ++r) {
            int row = lg * 4 + r;
            *(unsigned short*)(hb + row * HBP + (nj * 16 + lr) * 2) =
                f2b(fmaxf(acc[nj][r], 0.f));
        }
    asm volatile("s_waitcnt lgkmcnt(0)" ::: "memory");
    float bb2 = (lr < 2) ? b2[lr] : 0.f;
    f32x4 acc2 = (f32x4){bb2, bb2, bb2, bb2};
#pragma unroll
    for (int ks = 0; ks < 4; ++ks) {
        short8 a2 = *(const short8*)(hb + lr * HBP + ks * 64 + lg * 16);
        short8 bz = *(const short8*)&w2p[lr * 128 + ks * 32 + lg * 8];
        acc2 = MFMA_BF16(a2, bz, acc2, 0, 0, 0);
    }
    asm volatile("s_waitcnt lgkmcnt(0)" ::: "memory");
    if (lr < 2) {
#pragma unroll
        for (int r = 0; r < 4; ++r) {
            int gpo = gp0 + lg * 4 + r;
            float v = acc2[r];
            if (lr == 0) {
                out[gpo * 2] = v;
            } else {
                float sp = (v > 20.f) ? v : log1pf(expf(v));
                out[gpo * 2 + 1] = sp + 0.01f;
            }
        }
    }
}

// ---------------------------------------------------------------------------
extern "C" void kernel_launch(void* const* d_in, const int* in_sizes, int n_in,
                              void* d_out, int out_size, void* d_ws, size_t ws_size,
                              hipStream_t stream) {
    const float* h_grid = (const float*)d_in[0];
    const float* xs = (const float*)d_in[1];
    const float* ys = (const float*)d_in[2];
    const float* Bm = (const float*)d_in[3];
    const float* W0 = (const float*)d_in[4];
    const float* b0 = (const float*)d_in[5];
    const float* W1 = (const float*)d_in[6];
    const float* b1 = (const float*)d_in[7];
    const float* W2 = (const float*)d_in[8];
    const float* b2 = (const float*)d_in[9];
    float* out = (float*)d_out;

    unsigned short* ht  = (unsigned short*)d_ws;
    unsigned short* w0t = (unsigned short*)((char*)d_ws + 134217728ull);
    unsigned short* w1t = w0t + 128 * 384;
    unsigned short* w2p = w1t + 128 * 128;

    transpose_h<<<dim3(8192), dim3(256), 0, stream>>>(h_grid, ht);
    prep_weights<<<dim3(64), dim3(256), 0, stream>>>(W0, W1, W2, w0t, w1t, w2p);
    fused_decoder<<<dim3(2048), dim3(512), 0, stream>>>(ht, xs, ys, Bm, w0t, b0, w1t, b1, w2p, b2, out);
}